// Round 3
// baseline (2618.585 us; speedup 1.0000x reference)
//
#include <hip/hip_runtime.h>
#include <hip/hip_bf16.h>

constexpr int TT = 512, BB = 2048, KPH = 48, NOUT = 8;

__device__ __forceinline__ float sigm(float x) {
    return 1.f / (1.f + exp2f(x * -1.4426950408889634f));
}
__device__ __forceinline__ float tanh_(float x) {
    return 1.f - 2.f / (exp2f(x * 2.8853900817779268f) + 1.f);
}
__device__ __forceinline__ float bf2f(unsigned u) { return __uint_as_float(u << 16); }
__device__ __forceinline__ void wbar() { __builtin_amdgcn_wave_barrier(); }
// wait lgkmcnt(0) only (vmcnt=63, expcnt=7 -> no wait on those)
__device__ __forceinline__ void lgkm0() { __builtin_amdgcn_s_waitcnt(0xC07F); }

// Wave-autonomous BiGRU layer. block = 256 = 4 waves; each wave owns 2 batch
// elements for the entire kernel. lane = bl(1b) x u(5b): u = hidden unit
// (23 active of 32). Per lane: W_hh rows (r,z,n) in registers, xg for 8 steps
// in registers, h carried via per-wave LDS broadcast slot with within-wave
// ordering only (no __syncthreads after init). grid = (BB/8, 2 dirs).
template <bool L0>
__global__ __launch_bounds__(256) void gru_wave(
    const void* __restrict__ in_, const float* __restrict__ fmean,
    const float* __restrict__ fstd, const float* __restrict__ wih_g,
    const float* __restrict__ whh_g, const float* __restrict__ bih_g,
    const float* __restrict__ bhh_g, __hip_bfloat16* __restrict__ outbuf,
    float* __restrict__ lastbuf, int lastOnly)
{
    constexpr int KIN = L0 ? 32 : 46;
    constexpr int XP  = L0 ? 36 : 52;   // padded input-row stride (floats)
    constexpr int KV4 = L0 ? 8 : 12;    // float4 chunks per input row

    __shared__ __align__(16) float wih_s[80 * XP];   // rows padded to 80, zeros
    __shared__ __align__(16) float whh_s[80 * 24];
    __shared__ __align__(16) float xin_s[4 * 8 * 2 * XP]; // [wave][t][bl][XP]
    __shared__ __align__(16) float h_s[4 * 72];      // [wave][bl*36 + 24]
    __shared__ float bih_s[80], bhh_s[80];
    __shared__ __align__(16) float an_s[32], cn_s[32];

    const int tid  = threadIdx.x;
    const int wv   = tid >> 6;
    const int lane = tid & 63;
    const int bl   = lane >> 5;
    const int u    = lane & 31;
    const int dir  = blockIdx.y;
    const int bg   = blockIdx.x * 8 + wv * 2 + bl;

    const float* wih_d = wih_g + dir * 69 * KIN;
    const float* whh_d = whh_g + dir * 69 * 23;

    for (int idx = tid; idx < 80 * XP; idx += 256) {
        int j = idx / XP, k = idx - j * XP;
        wih_s[idx] = (j < 69 && k < KIN) ? wih_d[j * KIN + k] : 0.f;
    }
    for (int idx = tid; idx < 80 * 24; idx += 256) {
        int j = idx / 24, k = idx - j * 24;
        whh_s[idx] = (j < 69 && k < 23) ? whh_d[j * 23 + k] : 0.f;
    }
    for (int idx = tid; idx < 80; idx += 256) {
        bih_s[idx] = (idx < 69) ? bih_g[dir * 69 + idx] : 0.f;
        bhh_s[idx] = (idx < 69) ? bhh_g[dir * 69 + idx] : 0.f;
    }
    for (int idx = tid; idx < 4 * 72; idx += 256) h_s[idx] = 0.f;
    if (L0 && tid < 32) {
        float sd = fstd[tid];
        float sa = (sd == 0.f) ? 1.f : sd;        // std==0 -> 1
        float a  = (sa == 1.f) ? 0.f : 1.f / sa;  // adjusted std==1 -> zero
        an_s[tid] = a;
        cn_s[tid] = -fmean[tid] * a;
    }
    __syncthreads();   // the only block-wide barrier

    // per-lane W_hh rows (u, 23+u, 46+u), 24-padded cols -> registers
    float4 wr[3][6];
    float  bh[3], bi[3];
    #pragma unroll
    for (int r = 0; r < 3; ++r) {
        int row = r * 23 + u;          // <= 77 < 80, pad rows are zero
        #pragma unroll
        for (int k = 0; k < 6; ++k)
            wr[r][k] = *(const float4*)&whh_s[row * 24 + 4 * k];
        bh[r] = bhh_s[row];
        bi[r] = bih_s[row];
    }

    float* xw = &xin_s[wv * (16 * XP)];
    float* hw = &h_s[wv * 72];
    const int ngroups = (lastOnly && dir == 1) ? 1 : 64;
    float hold = 0.f;

    for (int g = 0; g < ngroups; ++g) {
        // ---- stage this wave's 2 batches x 8 timesteps into LDS (fp32) ----
        if constexpr (L0) {
            #pragma unroll
            for (int p = 0; p < 2; ++p) {
                int tau = lane + 64 * p;          // 2b x 8t x 8 float4
                int b2 = tau >> 6, tl = (tau >> 3) & 7, q = tau & 7;
                int tg = dir ? (511 - (g * 8 + tl)) : (g * 8 + tl);
                int bb2 = blockIdx.x * 8 + wv * 2 + b2;
                float4 xv = *(const float4*)((const float*)in_ +
                             ((size_t)bb2 * TT + tg) * 32 + 4 * q);
                float4 a4 = *(const float4*)&an_s[4 * q];
                float4 c4 = *(const float4*)&cn_s[4 * q];
                float4 o;
                o.x = xv.x * a4.x + c4.x; o.y = xv.y * a4.y + c4.y;
                o.z = xv.z * a4.z + c4.z; o.w = xv.w * a4.w + c4.w;
                *(float4*)&xw[(tl * 2 + b2) * XP + 4 * q] = o;
            }
        } else {
            #pragma unroll
            for (int p = 0; p < 3; ++p) {
                int tau = lane + 64 * p;          // 2b x 8t x 12 uint2
                int tl = tau / 24, rem = tau - 24 * tl;
                int b2 = rem / 12, q = rem - 12 * b2;
                int tg = dir ? (511 - (g * 8 + tl)) : (g * 8 + tl);
                int bb2 = blockIdx.x * 8 + wv * 2 + b2;
                uint2 v = *(const uint2*)((const unsigned short*)in_ +
                           ((size_t)tg * BB + bb2) * KPH + 4 * q);
                float4 o;
                o.x = bf2f(v.x & 0xffffu); o.y = bf2f(v.x >> 16);
                o.z = bf2f(v.y & 0xffffu); o.w = bf2f(v.y >> 16);
                *(float4*)&xw[(tl * 2 + b2) * XP + 4 * q] = o;
            }
        }
        lgkm0(); wbar();   // wave-local: staged data visible to this wave

        // ---- phase A: xg for 8 steps, 3 rows/lane, accum in registers ----
        float xg[8][3];
        #pragma unroll
        for (int t = 0; t < 8; ++t) {
            xg[t][0] = bi[0]; xg[t][1] = bi[1]; xg[t][2] = bi[2];
        }
        for (int k4 = 0; k4 < KV4; ++k4) {
            float4 w0 = *(const float4*)&wih_s[u * XP + 4 * k4];
            float4 w1 = *(const float4*)&wih_s[(23 + u) * XP + 4 * k4];
            float4 w2 = *(const float4*)&wih_s[(46 + u) * XP + 4 * k4];
            #pragma unroll
            for (int t = 0; t < 8; ++t) {
                float4 xt = *(const float4*)&xw[(t * 2 + bl) * XP + 4 * k4];
                xg[t][0] += w0.x * xt.x + w0.y * xt.y + w0.z * xt.z + w0.w * xt.w;
                xg[t][1] += w1.x * xt.x + w1.y * xt.y + w1.z * xt.z + w1.w * xt.w;
                xg[t][2] += w2.x * xt.x + w2.y * xt.y + w2.z * xt.z + w2.w * xt.w;
            }
        }

        // ---- 8 scan steps, barrier-free (within-wave LDS h broadcast) ----
        #pragma unroll
        for (int s8 = 0; s8 < 8; ++s8) {
            float a0 = bh[0], a1 = bh[1], a2 = bh[2];
            #pragma unroll
            for (int k = 0; k < 6; ++k) {
                float4 hv = *(const float4*)&hw[bl * 36 + 4 * k];
                float4 w;
                w = wr[0][k]; a0 += w.x * hv.x + w.y * hv.y + w.z * hv.z + w.w * hv.w;
                w = wr[1][k]; a1 += w.x * hv.x + w.y * hv.y + w.z * hv.z + w.w * hv.w;
                w = wr[2][k]; a2 += w.x * hv.x + w.y * hv.y + w.z * hv.z + w.w * hv.w;
            }
            float r_ = sigm(xg[s8][0] + a0);
            float z_ = sigm(xg[s8][1] + a1);
            float n_ = tanh_(xg[s8][2] + r_ * a2);
            float hnew = n_ + z_ * (hold - n_);   // (1-z)n + z h
            hold = hnew;                           // pad lanes stay 0 forever
            int tg = dir ? (511 - (g * 8 + s8)) : (g * 8 + s8);
            if (!lastOnly) {
                if (u < 23)
                    outbuf[((size_t)tg * BB + bg) * KPH + dir * 23 + u] =
                        __float2bfloat16(hnew);
            } else if (u < 23 && tg == TT - 1) {
                lastbuf[bg * KPH + dir * 23 + u] = hnew;
            }
            wbar();
            hw[bl * 36 + u] = hnew;
            lgkm0(); wbar();   // h visible to whole wave before next read
        }
    }
}

__global__ __launch_bounds__(256) void fc_kernel(
    const float* __restrict__ last, const float* __restrict__ fcw,
    const float* __restrict__ fcb, const float* __restrict__ ostd,
    const float* __restrict__ omean, float* __restrict__ out)
{
    int idx = blockIdx.x * 256 + threadIdx.x;
    if (idx >= BB * NOUT) return;
    int b = idx >> 3, o = idx & 7;
    float acc = fcb[o];
    const float* lr = last + b * KPH;
    const float* wr = fcw + o * 46;
    #pragma unroll
    for (int i = 0; i < 46; i++) acc += lr[i] * wr[i];
    out[idx] = acc * ostd[o] + omean[o];
}

extern "C" void kernel_launch(void* const* d_in, const int* in_sizes, int n_in,
                              void* d_out, int out_size, void* d_ws,
                              size_t ws_size, hipStream_t stream)
{
    const float* x     = (const float*)d_in[0];
    const float* fmean = (const float*)d_in[1];
    const float* fstd  = (const float*)d_in[2];
    const float* omean = (const float*)d_in[3];
    const float* ostd  = (const float*)d_in[4];
    const float* wih0  = (const float*)d_in[5];
    const float* whh0  = (const float*)d_in[6];
    const float* bih0  = (const float*)d_in[7];
    const float* bhh0  = (const float*)d_in[8];
    const float* wihr  = (const float*)d_in[9];
    const float* whhr  = (const float*)d_in[10];
    const float* bihr  = (const float*)d_in[11];
    const float* bhhr  = (const float*)d_in[12];
    const float* fcw   = (const float*)d_in[13];
    const float* fcb   = (const float*)d_in[14];

    char* ws = (char*)d_ws;
    const size_t bufBytes = (size_t)TT * BB * KPH * sizeof(__hip_bfloat16); // 96 MiB
    __hip_bfloat16* buf0 = (__hip_bfloat16*)ws;
    __hip_bfloat16* buf1 = (__hip_bfloat16*)(ws + bufBytes);
    float* lastb         = (float*)(ws + 2 * bufBytes);

    dim3 grid(BB / 8, 2);

    gru_wave<true><<<grid, 256, 0, stream>>>(x, fmean, fstd, wih0, whh0, bih0,
                                             bhh0, buf0, nullptr, 0);
    gru_wave<false><<<grid, 256, 0, stream>>>(
        buf0, nullptr, nullptr, wihr + 0 * 2 * 69 * 46, whhr + 0 * 2 * 69 * 23,
        bihr + 0 * 2 * 69, bhhr + 0 * 2 * 69, buf1, nullptr, 0);
    gru_wave<false><<<grid, 256, 0, stream>>>(
        buf1, nullptr, nullptr, wihr + 1 * 2 * 69 * 46, whhr + 1 * 2 * 69 * 23,
        bihr + 1 * 2 * 69, bhhr + 1 * 2 * 69, nullptr, lastb, 1);
    fc_kernel<<<(BB * NOUT + 255) / 256, 256, 0, stream>>>(lastb, fcw, fcb, ostd,
                                                           omean, (float*)d_out);
}

// Round 4
// 2423.783 us; speedup vs baseline: 1.0804x; 1.0804x over previous
//
#include <hip/hip_runtime.h>
#include <hip/hip_bf16.h>

constexpr int TT = 512, BB = 2048, NOUT = 8;
constexpr size_t DSTRIDE = (size_t)BB * TT * 24;   // bf16 elems per dir region

__device__ __forceinline__ float sigm(float x) {
    return 1.f / (1.f + exp2f(x * -1.4426950408889634f));
}
__device__ __forceinline__ float tanh_(float x) {
    return 1.f - 2.f / (exp2f(x * 2.8853900817779268f) + 1.f);
}
__device__ __forceinline__ float bf2f(unsigned u) { return __uint_as_float(u << 16); }
__device__ __forceinline__ unsigned f2bf(float x) {
    __hip_bfloat16 h = __float2bfloat16(x);
    unsigned short s;
    __builtin_memcpy(&s, &h, 2);
    return (unsigned)s;
}
__device__ __forceinline__ void wbar() { __builtin_amdgcn_wave_barrier(); }
// wait lgkmcnt(0) only (vmcnt=63, expcnt=7)
__device__ __forceinline__ void lgkm0() { __builtin_amdgcn_s_waitcnt(0xC07F); }

// Wave-autonomous BiGRU layer, batch-major IO. block = 256 = 4 waves; each
// wave owns 2 batch elems. lane = bl(1) x u(5). W_hh rows in registers, xg for
// 8 steps in registers, h history in per-wave LDS [9][2][24] (row 0 = carry).
// Inter-layer buffers: [dir][b][t][24] bf16 -> per-group cooperative store of
// 384B fully-covered line-aligned blocks (no partial-line RMW).
template <bool L0>
__global__ __launch_bounds__(256) void gru_wave(
    const void* __restrict__ in_,        // L0: x [B][T][32] f32; else fwd region (bwd = +DSTRIDE)
    const float* __restrict__ fmean, const float* __restrict__ fstd,
    const float* __restrict__ wih_g, const float* __restrict__ whh_g,
    const float* __restrict__ bih_g, const float* __restrict__ bhh_g,
    __hip_bfloat16* __restrict__ outbuf,  // dual-region dest (null if lastOnly)
    float* __restrict__ lastbuf, int lastOnly)
{
    constexpr int KIN = L0 ? 32 : 46;
    constexpr int XP  = L0 ? 36 : 52;   // xin row stride; non-L0 cols: fwd 0..23, bwd 24..47
    constexpr int KV4 = L0 ? 8 : 12;

    __shared__ __align__(16) float wih_s[80 * XP];
    __shared__ __align__(16) float whh_s[80 * 24];
    __shared__ __align__(16) float xin_s[4 * 16 * XP];     // [wave][t*2+bl][XP]
    __shared__ __align__(16) float hist_s[4 * 9 * 2 * 24]; // [wave][row][bl][24]
    __shared__ float bih_s[80], bhh_s[80];
    __shared__ __align__(16) float an_s[32], cn_s[32];

    const int tid = threadIdx.x, wv = tid >> 6, lane = tid & 63;
    const int bl = lane >> 5, u = lane & 31;
    const int dir = blockIdx.y;
    const int bg  = blockIdx.x * 8 + wv * 2 + bl;

    const float* wih_d = wih_g + dir * 69 * KIN;
    const float* whh_d = whh_g + dir * 69 * 23;

    // ---- stage weights (cols remapped: non-L0 dest col 23/47 = 0) ----
    for (int idx = tid; idx < 80 * XP; idx += 256) {
        int j = idx / XP, d = idx - j * XP;
        float v = 0.f;
        if (j < 69) {
            if constexpr (L0) {
                if (d < 32) v = wih_d[j * 32 + d];
            } else {
                if (d < 23) v = wih_d[j * 46 + d];
                else if (d >= 24 && d < 47) v = wih_d[j * 46 + d - 1];
            }
        }
        wih_s[idx] = v;
    }
    for (int idx = tid; idx < 80 * 24; idx += 256) {
        int j = idx / 24, k = idx - j * 24;
        whh_s[idx] = (j < 69 && k < 23) ? whh_d[j * 23 + k] : 0.f;
    }
    for (int idx = tid; idx < 80; idx += 256) {
        bih_s[idx] = (idx < 69) ? bih_g[dir * 69 + idx] : 0.f;
        bhh_s[idx] = (idx < 69) ? bhh_g[dir * 69 + idx] : 0.f;
    }
    for (int idx = tid; idx < 4 * 9 * 2 * 24; idx += 256) hist_s[idx] = 0.f;
    if (L0 && tid < 32) {
        float sd = fstd[tid];
        float sa = (sd == 0.f) ? 1.f : sd;        // std==0 -> 1
        float a  = (sa == 1.f) ? 0.f : 1.f / sa;  // adjusted std==1 -> zero
        an_s[tid] = a;
        cn_s[tid] = -fmean[tid] * a;
    }
    __syncthreads();   // only block-wide barrier

    // per-lane W_hh rows (u, 23+u, 46+u) -> registers
    float4 wr[3][6];
    float  bh[3], bi[3];
    #pragma unroll
    for (int r = 0; r < 3; ++r) {
        int row = r * 23 + u;   // <= 77 < 80
        #pragma unroll
        for (int k = 0; k < 6; ++k)
            wr[r][k] = *(const float4*)&whh_s[row * 24 + 4 * k];
        bh[r] = bhh_s[row];
        bi[r] = bih_s[row];
    }

    float* xw = &xin_s[wv * 16 * XP];
    float* hw = &hist_s[wv * 9 * 2 * 24];
    const int ngroups = (lastOnly && dir == 1) ? 1 : 64;
    float hold = 0.f;

    for (int g = 0; g < ngroups; ++g) {
        const int tw0 = dir ? (504 - g * 8) : g * 8;   // memory window base row

        // ---- stage 2b x 8t inputs into xin (fp32) ----
        if constexpr (L0) {
            #pragma unroll
            for (int p = 0; p < 2; ++p) {
                int tau = lane + 64 * p;                 // 2b x 8row x 8 float4
                int b2 = tau >> 6, rw = (tau >> 3) & 7, q = tau & 7;
                int bb2 = blockIdx.x * 8 + wv * 2 + b2;
                float4 xv = *(const float4*)((const float*)in_ +
                             ((size_t)bb2 * TT + tw0 + rw) * 32 + 4 * q);
                float4 a4 = *(const float4*)&an_s[4 * q];
                float4 c4 = *(const float4*)&cn_s[4 * q];
                float4 o;
                o.x = xv.x * a4.x + c4.x; o.y = xv.y * a4.y + c4.y;
                o.z = xv.z * a4.z + c4.z; o.w = xv.w * a4.w + c4.w;
                int tl = dir ? (7 - rw) : rw;
                *(float4*)&xw[(tl * 2 + b2) * XP + 4 * q] = o;
            }
        } else {
            #pragma unroll
            for (int p = 0; p < 2; ++p) {
                int tau = lane + 64 * p;                 // 96 tasks: 2b x 2src x 8row x 3chunk
                if (tau < 96) {
                    int b2 = tau / 48, rem = tau - 48 * b2;
                    int src = rem / 24, rc = rem - 24 * src;
                    int rw = rc / 3, c = rc - 3 * rw;
                    int bb2 = blockIdx.x * 8 + wv * 2 + b2;
                    const unsigned short* srcp =
                        (const unsigned short*)in_ + src * DSTRIDE;
                    uint4 v = *(const uint4*)(srcp +
                               ((size_t)bb2 * TT + tw0 + rw) * 24 + 8 * c);
                    int tl = dir ? (7 - rw) : rw;
                    float* dst = &xw[(tl * 2 + b2) * XP + src * 24 + 8 * c];
                    float4 o0, o1;
                    o0.x = bf2f(v.x & 0xffffu); o0.y = bf2f(v.x >> 16);
                    o0.z = bf2f(v.y & 0xffffu); o0.w = bf2f(v.y >> 16);
                    o1.x = bf2f(v.z & 0xffffu); o1.y = bf2f(v.z >> 16);
                    o1.z = bf2f(v.w & 0xffffu); o1.w = bf2f(v.w >> 16);
                    *(float4*)dst = o0;
                    *(float4*)(dst + 4) = o1;
                }
            }
        }
        lgkm0(); wbar();

        // ---- phase A: xg for 8 steps (no h dependence) ----
        float xg[8][3];
        #pragma unroll
        for (int t = 0; t < 8; ++t) {
            xg[t][0] = bi[0]; xg[t][1] = bi[1]; xg[t][2] = bi[2];
        }
        for (int k4 = 0; k4 < KV4; ++k4) {
            float4 w0 = *(const float4*)&wih_s[u * XP + 4 * k4];
            float4 w1 = *(const float4*)&wih_s[(23 + u) * XP + 4 * k4];
            float4 w2 = *(const float4*)&wih_s[(46 + u) * XP + 4 * k4];
            #pragma unroll
            for (int t = 0; t < 8; ++t) {
                float4 xt = *(const float4*)&xw[(t * 2 + bl) * XP + 4 * k4];
                xg[t][0] += w0.x * xt.x + w0.y * xt.y + w0.z * xt.z + w0.w * xt.w;
                xg[t][1] += w1.x * xt.x + w1.y * xt.y + w1.z * xt.z + w1.w * xt.w;
                xg[t][2] += w2.x * xt.x + w2.y * xt.y + w2.z * xt.z + w2.w * xt.w;
            }
        }

        // ---- 8 scan steps, within-wave fences only ----
        #pragma unroll
        for (int s8 = 0; s8 < 8; ++s8) {
            const float* hr = &hw[(s8 * 2 + bl) * 24];   // row s8 = prev h
            float a0 = bh[0], a1 = bh[1], a2 = bh[2];
            #pragma unroll
            for (int k = 0; k < 6; ++k) {
                float4 hv = *(const float4*)&hr[4 * k];
                float4 w;
                w = wr[0][k]; a0 += w.x * hv.x + w.y * hv.y + w.z * hv.z + w.w * hv.w;
                w = wr[1][k]; a1 += w.x * hv.x + w.y * hv.y + w.z * hv.z + w.w * hv.w;
                w = wr[2][k]; a2 += w.x * hv.x + w.y * hv.y + w.z * hv.z + w.w * hv.w;
            }
            float r_ = sigm(xg[s8][0] + a0);
            float z_ = sigm(xg[s8][1] + a1);
            float n_ = tanh_(xg[s8][2] + r_ * a2);
            float hnew = n_ + z_ * (hold - n_);
            hold = hnew;
            if (lastOnly && u < 23) {
                int tg = dir ? (511 - (g * 8 + s8)) : (g * 8 + s8);
                if (tg == TT - 1) lastbuf[bg * 48 + dir * 23 + u] = hnew;
            }
            wbar();
            hw[((s8 + 1) * 2 + bl) * 24 + u] = hnew;
            lgkm0(); wbar();
        }

        // ---- cooperative coalesced store of the 8-step block ----
        if (!lastOnly) {
            int b2 = lane >> 5, idx = lane & 31;
            int bb2 = blockIdx.x * 8 + wv * 2 + b2;
            unsigned short* dst =
                (unsigned short*)outbuf + dir * DSTRIDE + (size_t)bb2 * TT * 24;
            #pragma unroll
            for (int c = 0; c < 3; ++c) {
                int p = idx + 32 * c;             // 0..95
                int s = p / 12, cp = p - 12 * s;  // step, col-pair
                float2 hv = *(const float2*)&hw[((s + 1) * 2 + b2) * 24 + 2 * cp];
                if (cp == 11) hv.y = 0.f;         // col 23 := 0
                unsigned pack = f2bf(hv.x) | (f2bf(hv.y) << 16);
                int tg = dir ? (511 - (g * 8 + s)) : (g * 8 + s);
                *(unsigned*)(dst + (size_t)tg * 24 + 2 * cp) = pack;
            }
        }
        // carry h into row 0 for next group
        hw[bl * 24 + u] = hold;
    }
}

__global__ __launch_bounds__(256) void fc_kernel(
    const float* __restrict__ last, const float* __restrict__ fcw,
    const float* __restrict__ fcb, const float* __restrict__ ostd,
    const float* __restrict__ omean, float* __restrict__ out)
{
    int idx = blockIdx.x * 256 + threadIdx.x;
    if (idx >= BB * NOUT) return;
    int b = idx >> 3, o = idx & 7;
    float acc = fcb[o];
    const float* lr = last + b * 48;
    const float* wr = fcw + o * 46;
    #pragma unroll
    for (int i = 0; i < 46; i++) acc += lr[i] * wr[i];
    out[idx] = acc * ostd[o] + omean[o];
}

extern "C" void kernel_launch(void* const* d_in, const int* in_sizes, int n_in,
                              void* d_out, int out_size, void* d_ws,
                              size_t ws_size, hipStream_t stream)
{
    const float* x     = (const float*)d_in[0];
    const float* fmean = (const float*)d_in[1];
    const float* fstd  = (const float*)d_in[2];
    const float* omean = (const float*)d_in[3];
    const float* ostd  = (const float*)d_in[4];
    const float* wih0  = (const float*)d_in[5];
    const float* whh0  = (const float*)d_in[6];
    const float* bih0  = (const float*)d_in[7];
    const float* bhh0  = (const float*)d_in[8];
    const float* wihr  = (const float*)d_in[9];
    const float* whhr  = (const float*)d_in[10];
    const float* bihr  = (const float*)d_in[11];
    const float* bhhr  = (const float*)d_in[12];
    const float* fcw   = (const float*)d_in[13];
    const float* fcb   = (const float*)d_in[14];

    char* ws = (char*)d_ws;
    const size_t bufBytes = 2 * DSTRIDE * sizeof(__hip_bfloat16);  // 96 MiB
    __hip_bfloat16* buf0 = (__hip_bfloat16*)ws;
    __hip_bfloat16* buf1 = (__hip_bfloat16*)(ws + bufBytes);
    float* lastb         = (float*)(ws + 2 * bufBytes);

    dim3 grid(BB / 8, 2);

    gru_wave<true><<<grid, 256, 0, stream>>>(x, fmean, fstd, wih0, whh0, bih0,
                                             bhh0, buf0, nullptr, 0);
    gru_wave<false><<<grid, 256, 0, stream>>>(
        buf0, nullptr, nullptr, wihr + 0 * 2 * 69 * 46, whhr + 0 * 2 * 69 * 23,
        bihr + 0 * 2 * 69, bhhr + 0 * 2 * 69, buf1, nullptr, 0);
    gru_wave<false><<<grid, 256, 0, stream>>>(
        buf1, nullptr, nullptr, wihr + 1 * 2 * 69 * 46, whhr + 1 * 2 * 69 * 23,
        bihr + 1 * 2 * 69, bhhr + 1 * 2 * 69, nullptr, lastb, 1);
    fc_kernel<<<(BB * NOUT + 255) / 256, 256, 0, stream>>>(lastb, fcw, fcb, ostd,
                                                           omean, (float*)d_out);
}

// Round 5
// 1030.506 us; speedup vs baseline: 2.5411x; 2.3520x over previous
//
#include <hip/hip_runtime.h>
#include <hip/hip_bf16.h>

constexpr int TT = 512, BB = 2048, NOUT = 8;
constexpr size_t DSTRIDE = (size_t)BB * TT * 24;   // bf16 elems per dir region

typedef __attribute__((ext_vector_type(8))) short bf16x8;
typedef __attribute__((ext_vector_type(4))) float f32x4;

__device__ __forceinline__ float sigm(float x) {
    return 1.f / (1.f + exp2f(x * -1.4426950408889634f));
}
__device__ __forceinline__ float tanh_(float x) {
    return 1.f - 2.f / (exp2f(x * 2.8853900817779268f) + 1.f);
}
__device__ __forceinline__ float bf2f(unsigned u) { return __uint_as_float(u << 16); }
__device__ __forceinline__ unsigned short f2bf(float x) {
    __hip_bfloat16 h = __float2bfloat16(x);
    unsigned short s;
    __builtin_memcpy(&s, &h, 2);
    return s;
}
__device__ __forceinline__ void wbar() { __builtin_amdgcn_wave_barrier(); }
// wait lgkmcnt(0) only (vmcnt=63, expcnt=7)
__device__ __forceinline__ void lgkm0() { __builtin_amdgcn_s_waitcnt(0xC07F); }

// Wave-autonomous BiGRU layer; input-side gates via MFMA.
// block = 256 = 4 waves; wave owns 2 batch elems end-to-end. Per 8-step group:
// 16x80x64 GEMM (A = bf16 activations direct from global, B = W_ih bf16 frags
// in regs) -> D through per-wave LDS tile -> scan lanes (bl,u) consume it.
// Scan: W_hh rows in regs, h history per-wave LDS, within-wave fences only.
// Inter-layer buffers: [dir][b][t][24] bf16, full-line cooperative stores.
template <bool L0>
__global__ __launch_bounds__(256) void gru_mfma(
    const void* __restrict__ in_,        // L0: x [B][T][32] f32; else region0 (region1 at +DSTRIDE)
    const float* __restrict__ fmean, const float* __restrict__ fstd,
    const float* __restrict__ wih_g, const float* __restrict__ whh_g,
    const float* __restrict__ bih_g, const float* __restrict__ bhh_g,
    __hip_bfloat16* __restrict__ outbuf, float* __restrict__ lastbuf,
    int lastOnly)
{
    constexpr int KIN = L0 ? 32 : 46;
    constexpr int KF  = L0 ? 1 : 2;      // K-fragments of 32 (K padded to 64)

    __shared__ __align__(16) short  wih_lds[80 * 64];     // B^T bf16, remapped cols
    __shared__ __align__(16) float  whh_s[80 * 24];
    __shared__ __align__(16) float  xg_s[4][16 * 84];     // per-wave D tile [m][84]
    __shared__ __align__(16) float  hist_s[4 * 9 * 2 * 24];
    __shared__ float bih_s[80], bhh_s[80];
    __shared__ __align__(16) float an_s[32], cn_s[32];

    const int tid = threadIdx.x, wv = tid >> 6, lane = tid & 63;
    const int bl = lane >> 5, u = lane & 31;
    const int m  = lane & 15, kg = lane >> 4;             // MFMA A/B lane coords
    const int dir = blockIdx.y;
    const int bg  = blockIdx.x * 8 + wv * 2 + bl;

    const float* wih_d = wih_g + dir * 69 * KIN;
    const float* whh_d = whh_g + dir * 69 * 23;

    // ---- stage W_ih as bf16 B^T [80 rows][64 k-slots], col-remapped ----
    for (int idx = tid; idx < 80 * 64; idx += 256) {
        int n = idx >> 6, k = idx & 63;
        float v = 0.f;
        if (n < 69) {
            if constexpr (L0) {
                if (k < 32) v = wih_d[n * 32 + k];
            } else {
                if (k < 23) v = wih_d[n * 46 + k];           // fwd h cols
                else if (k >= 24 && k < 47) v = wih_d[n * 46 + k - 1];  // bwd
            }
        }
        wih_lds[idx] = (short)f2bf(v);
    }
    for (int idx = tid; idx < 80 * 24; idx += 256) {
        int j = idx / 24, k = idx - j * 24;
        whh_s[idx] = (j < 69 && k < 23) ? whh_d[j * 23 + k] : 0.f;
    }
    for (int idx = tid; idx < 80; idx += 256) {
        bih_s[idx] = (idx < 69) ? bih_g[dir * 69 + idx] : 0.f;
        bhh_s[idx] = (idx < 69) ? bhh_g[dir * 69 + idx] : 0.f;
    }
    for (int idx = tid; idx < 4 * 9 * 2 * 24; idx += 256) hist_s[idx] = 0.f;
    if (L0 && tid < 32) {
        float sd = fstd[tid];
        float sa = (sd == 0.f) ? 1.f : sd;        // std==0 -> 1
        float a  = (sa == 1.f) ? 0.f : 1.f / sa;  // adjusted std==1 -> zero
        an_s[tid] = a;
        cn_s[tid] = -fmean[tid] * a;
    }
    __syncthreads();   // only block-wide barrier

    // ---- per-lane W_hh rows (u, 23+u, 46+u) -> registers ----
    float4 wr[3][6];
    float  bh[3], bi[3];
    #pragma unroll
    for (int r = 0; r < 3; ++r) {
        int row = r * 23 + u;   // <= 77 < 80
        #pragma unroll
        for (int k = 0; k < 6; ++k)
            wr[r][k] = *(const float4*)&whh_s[row * 24 + 4 * k];
        bh[r] = bhh_s[row];
        bi[r] = bih_s[row];
    }

    // ---- B-fragments (W_ih) -> registers, kept whole kernel ----
    bf16x8 bfr[5][KF];
    #pragma unroll
    for (int tile = 0; tile < 5; ++tile)
        #pragma unroll
        for (int kf = 0; kf < KF; ++kf)
            bfr[tile][kf] = *(const bf16x8*)
                &wih_lds[(tile * 16 + m) * 64 + kf * 32 + kg * 8];

    float an8[L0 ? 8 : 1], cn8[L0 ? 8 : 1];
    if constexpr (L0) {
        #pragma unroll
        for (int j = 0; j < 8; ++j) {
            an8[j] = an_s[kg * 8 + j];
            cn8[j] = cn_s[kg * 8 + j];
        }
    }

    float* xw = &xg_s[wv][0];
    float* hw = &hist_s[wv * 9 * 2 * 24];
    const int ngroups = (lastOnly && dir == 1) ? 1 : 64;
    float hold = 0.f;

    // A-row coords: m = bl_a*8 + tl  (bl_a matches scan's bl for lanes' own b)
    const int bl_a = m >> 3, tl = m & 7;
    const int b_a  = blockIdx.x * 8 + wv * 2 + bl_a;

    for (int g = 0; g < ngroups; ++g) {
        const int tg_a = dir ? (511 - (g * 8 + tl)) : (g * 8 + tl);

        // ---- input-side gates via MFMA ----
        f32x4 acc[5];
        #pragma unroll
        for (int t = 0; t < 5; ++t) acc[t] = (f32x4){0.f, 0.f, 0.f, 0.f};

        if constexpr (L0) {
            const float* xr = (const float*)in_ + ((size_t)b_a * TT + tg_a) * 32 + kg * 8;
            float4 x0 = *(const float4*)xr;
            float4 x1 = *(const float4*)(xr + 4);
            float xv[8] = {x0.x, x0.y, x0.z, x0.w, x1.x, x1.y, x1.z, x1.w};
            bf16x8 afr;
            #pragma unroll
            for (int j = 0; j < 8; ++j)
                afr[j] = (short)f2bf(xv[j] * an8[j] + cn8[j]);
            #pragma unroll
            for (int t = 0; t < 5; ++t)
                acc[t] = __builtin_amdgcn_mfma_f32_16x16x32_bf16(afr, bfr[t][0],
                                                                 acc[t], 0, 0, 0);
        } else {
            const unsigned short* r0 = (const unsigned short*)in_;
            const unsigned short* r1 = r0 + DSTRIDE;
            size_t rowoff = ((size_t)b_a * TT + tg_a) * 24;
            // frag0: k 0..31 -> kg<3: fwd[8kg..]; kg==3: bwd[0..7]
            const unsigned short* p0 =
                (kg < 3) ? (r0 + rowoff + 8 * kg) : (r1 + rowoff);
            bf16x8 a0 = *(const bf16x8*)p0;
            // frag1: k 32..63 -> kg==0: bwd[8..15]; kg==1: bwd[16..23]; else 0
            const unsigned short* p1 =
                (kg == 0) ? (r1 + rowoff + 8) : (r1 + rowoff + 16);
            bf16x8 a1 = *(const bf16x8*)p1;
            if (kg >= 2) a1 = (bf16x8){0, 0, 0, 0, 0, 0, 0, 0};
            #pragma unroll
            for (int t = 0; t < 5; ++t) {
                acc[t] = __builtin_amdgcn_mfma_f32_16x16x32_bf16(a0, bfr[t][0],
                                                                 acc[t], 0, 0, 0);
                acc[t] = __builtin_amdgcn_mfma_f32_16x16x32_bf16(a1, bfr[t][1],
                                                                 acc[t], 0, 0, 0);
            }
        }

        // ---- D -> per-wave LDS tile [m2][84] (prev group fully consumed) ----
        lgkm0(); wbar();
        #pragma unroll
        for (int t = 0; t < 5; ++t) {
            #pragma unroll
            for (int reg = 0; reg < 4; ++reg) {
                int m2 = kg * 4 + reg;          // D row = (lane>>4)*4+reg
                int n  = t * 16 + m;            // D col = lane&15
                xw[m2 * 84 + n] = acc[t][reg];
            }
        }
        lgkm0(); wbar();

        // ---- pull this lane's xg (3 rows x 8 steps) into registers ----
        float xgv[8][3];
        #pragma unroll
        for (int s = 0; s < 8; ++s) {
            const float* xr2 = &xw[(bl * 8 + s) * 84];
            xgv[s][0] = xr2[u];
            xgv[s][1] = xr2[23 + u];
            xgv[s][2] = xr2[46 + u];
        }

        // ---- 8 scan steps, within-wave fences only ----
        #pragma unroll
        for (int s8 = 0; s8 < 8; ++s8) {
            const float* hr = &hw[(s8 * 2 + bl) * 24];   // row s8 = prev h
            float a0 = bh[0], a1 = bh[1], a2 = bh[2];
            #pragma unroll
            for (int k = 0; k < 6; ++k) {
                float4 hv = *(const float4*)&hr[4 * k];
                float4 w;
                w = wr[0][k]; a0 += w.x * hv.x + w.y * hv.y + w.z * hv.z + w.w * hv.w;
                w = wr[1][k]; a1 += w.x * hv.x + w.y * hv.y + w.z * hv.z + w.w * hv.w;
                w = wr[2][k]; a2 += w.x * hv.x + w.y * hv.y + w.z * hv.z + w.w * hv.w;
            }
            float r_ = sigm(xgv[s8][0] + bi[0] + a0);
            float z_ = sigm(xgv[s8][1] + bi[1] + a1);
            float n_ = tanh_(xgv[s8][2] + bi[2] + r_ * a2);
            float hnew = n_ + z_ * (hold - n_);
            hold = hnew;
            if (lastOnly && u < 23) {
                int tg = dir ? (511 - (g * 8 + s8)) : (g * 8 + s8);
                if (tg == TT - 1) lastbuf[bg * 48 + dir * 23 + u] = hnew;
            }
            wbar();
            if (u < 24) hw[((s8 + 1) * 2 + bl) * 24 + u] = hnew;
            lgkm0(); wbar();
        }

        // ---- cooperative coalesced store of the 8-step block ----
        if (!lastOnly) {
            int b2 = lane >> 5, idx = lane & 31;
            int bb2 = blockIdx.x * 8 + wv * 2 + b2;
            unsigned short* dst =
                (unsigned short*)outbuf + dir * DSTRIDE + (size_t)bb2 * TT * 24;
            #pragma unroll
            for (int c = 0; c < 3; ++c) {
                int p = idx + 32 * c;             // 0..95
                int s = p / 12, cp = p - 12 * s;  // step, col-pair
                float2 hv = *(const float2*)&hw[((s + 1) * 2 + b2) * 24 + 2 * cp];
                if (cp == 11) hv.y = 0.f;         // col 23 := 0
                unsigned pack = (unsigned)f2bf(hv.x) | ((unsigned)f2bf(hv.y) << 16);
                int tg = dir ? (511 - (g * 8 + s)) : (g * 8 + s);
                *(unsigned*)(dst + (size_t)tg * 24 + 2 * cp) = pack;
            }
        }
        // carry h into row 0 for next group
        if (u < 24) hw[bl * 24 + u] = hold;
    }
}

__global__ __launch_bounds__(256) void fc_kernel(
    const float* __restrict__ last, const float* __restrict__ fcw,
    const float* __restrict__ fcb, const float* __restrict__ ostd,
    const float* __restrict__ omean, float* __restrict__ out)
{
    int idx = blockIdx.x * 256 + threadIdx.x;
    if (idx >= BB * NOUT) return;
    int b = idx >> 3, o = idx & 7;
    float acc = fcb[o];
    const float* lr = last + b * 48;
    const float* wr = fcw + o * 46;
    #pragma unroll
    for (int i = 0; i < 46; i++) acc += lr[i] * wr[i];
    out[idx] = acc * ostd[o] + omean[o];
}

extern "C" void kernel_launch(void* const* d_in, const int* in_sizes, int n_in,
                              void* d_out, int out_size, void* d_ws,
                              size_t ws_size, hipStream_t stream)
{
    const float* x     = (const float*)d_in[0];
    const float* fmean = (const float*)d_in[1];
    const float* fstd  = (const float*)d_in[2];
    const float* omean = (const float*)d_in[3];
    const float* ostd  = (const float*)d_in[4];
    const float* wih0  = (const float*)d_in[5];
    const float* whh0  = (const float*)d_in[6];
    const float* bih0  = (const float*)d_in[7];
    const float* bhh0  = (const float*)d_in[8];
    const float* wihr  = (const float*)d_in[9];
    const float* whhr  = (const float*)d_in[10];
    const float* bihr  = (const float*)d_in[11];
    const float* bhhr  = (const float*)d_in[12];
    const float* fcw   = (const float*)d_in[13];
    const float* fcb   = (const float*)d_in[14];

    char* ws = (char*)d_ws;
    const size_t bufBytes = 2 * DSTRIDE * sizeof(__hip_bfloat16);  // 96 MiB
    __hip_bfloat16* buf0 = (__hip_bfloat16*)ws;
    __hip_bfloat16* buf1 = (__hip_bfloat16*)(ws + bufBytes);
    float* lastb         = (float*)(ws + 2 * bufBytes);

    dim3 grid(BB / 8, 2);

    gru_mfma<true><<<grid, 256, 0, stream>>>(x, fmean, fstd, wih0, whh0, bih0,
                                             bhh0, buf0, nullptr, 0);
    gru_mfma<false><<<grid, 256, 0, stream>>>(
        buf0, nullptr, nullptr, wihr + 0 * 2 * 69 * 46, whhr + 0 * 2 * 69 * 23,
        bihr + 0 * 2 * 69, bhhr + 0 * 2 * 69, buf1, nullptr, 0);
    gru_mfma<false><<<grid, 256, 0, stream>>>(
        buf1, nullptr, nullptr, wihr + 1 * 2 * 69 * 46, whhr + 1 * 2 * 69 * 23,
        bihr + 1 * 2 * 69, bhhr + 1 * 2 * 69, nullptr, lastb, 1);
    fc_kernel<<<(BB * NOUT + 255) / 256, 256, 0, stream>>>(lastb, fcw, fcb, ostd,
                                                           omean, (float*)d_out);
}

// Round 6
// 950.305 us; speedup vs baseline: 2.7555x; 1.0844x over previous
//
#include <hip/hip_runtime.h>
#include <hip/hip_bf16.h>

constexpr int TT = 512, BB = 2048, NOUT = 8;
constexpr size_t DSTRIDE = (size_t)BB * TT * 24;   // bf16 elems per dir region

typedef __attribute__((ext_vector_type(8))) short bf16x8;
typedef __attribute__((ext_vector_type(4))) float f32x4;
typedef __attribute__((ext_vector_type(2))) _Float16 f16x2;

__device__ __forceinline__ float sigm(float x) {
    return 1.f / (1.f + exp2f(x * -1.4426950408889634f));
}
__device__ __forceinline__ float tanh_(float x) {
    return 1.f - 2.f / (exp2f(x * 2.8853900817779268f) + 1.f);
}
__device__ __forceinline__ unsigned short f2bf(float x) {
    __hip_bfloat16 h = __float2bfloat16(x);
    unsigned short s;
    __builtin_memcpy(&s, &h, 2);
    return s;
}
__device__ __forceinline__ f16x2 asf16x2(unsigned v) {
    f16x2 r; __builtin_memcpy(&r, &v, 4); return r;
}
__device__ __forceinline__ void wbar() { __builtin_amdgcn_wave_barrier(); }
// wait lgkmcnt(0) only (vmcnt=63, expcnt=7)
__device__ __forceinline__ void lgkm0() { __builtin_amdgcn_s_waitcnt(0xC07F); }

// Wave-autonomous BiGRU layer; input gates via MFMA, hidden matvec via
// v_dot2_f32_f16 (W_hh as f16 pairs in 36 VGPRs, h broadcast as f16 in LDS).
// block = 256 = 4 waves; wave owns 2 batch elems. Within-wave fences only.
// Inter-layer buffers: [dir][b][t][24] bf16, full-line cooperative stores.
template <bool L0>
__global__ __launch_bounds__(256) void gru_mfma(
    const void* __restrict__ in_,        // L0: x [B][T][32] f32; else region0 (region1 at +DSTRIDE)
    const float* __restrict__ fmean, const float* __restrict__ fstd,
    const float* __restrict__ wih_g, const float* __restrict__ whh_g,
    const float* __restrict__ bih_g, const float* __restrict__ bhh_g,
    __hip_bfloat16* __restrict__ outbuf, float* __restrict__ lastbuf,
    int lastOnly)
{
    constexpr int KIN = L0 ? 32 : 46;

    __shared__ __align__(16) short     wih_lds[80 * 72];   // B^T bf16, stride 72
    __shared__ __align__(16) _Float16  whh_h[80 * 24];     // W_hh f16
    __shared__ __align__(16) float     xg_s[4][16 * 84];   // per-wave D tile
    __shared__ __align__(16) _Float16  hist_h[4 * 9 * 2 * 24];  // h history f16
    __shared__ float bih_s[80], bhh_s[80];
    __shared__ __align__(16) float an_s[32], cn_s[32];

    const int tid = threadIdx.x, wv = tid >> 6, lane = tid & 63;
    const int bl = lane >> 5, u = lane & 31;
    const int m  = lane & 15, kg = lane >> 4;             // MFMA lane coords
    const int dir = blockIdx.y;
    const int bg  = blockIdx.x * 8 + wv * 2 + bl;

    const float* wih_d = wih_g + dir * 69 * KIN;
    const float* whh_d = whh_g + dir * 69 * 23;

    // ---- stage W_ih as bf16 B^T [80][72], col-remapped ----
    for (int idx = tid; idx < 80 * 72; idx += 256) {
        int n = idx / 72, k = idx - n * 72;
        float v = 0.f;
        if (n < 69 && k < 64) {
            if constexpr (L0) {
                if (k < 32) v = wih_d[n * 32 + k];
            } else {
                if (k < 23) v = wih_d[n * 46 + k];                      // fwd
                else if (k >= 24 && k < 47) v = wih_d[n * 46 + k - 1];  // bwd
            }
        }
        wih_lds[idx] = (short)f2bf(v);
    }
    for (int idx = tid; idx < 80 * 24; idx += 256) {
        int j = idx / 24, k = idx - j * 24;
        whh_h[idx] = (j < 69 && k < 23) ? (_Float16)whh_d[j * 23 + k]
                                        : (_Float16)0.f;
    }
    for (int idx = tid; idx < 80; idx += 256) {
        bih_s[idx] = (idx < 69) ? bih_g[dir * 69 + idx] : 0.f;
        bhh_s[idx] = (idx < 69) ? bhh_g[dir * 69 + idx] : 0.f;
    }
    for (int idx = tid; idx < 4 * 9 * 2 * 24; idx += 256)
        hist_h[idx] = (_Float16)0.f;
    if (L0 && tid < 32) {
        float sd = fstd[tid];
        float sa = (sd == 0.f) ? 1.f : sd;        // std==0 -> 1
        float a  = (sa == 1.f) ? 0.f : 1.f / sa;  // adjusted std==1 -> zero
        an_s[tid] = a;
        cn_s[tid] = -fmean[tid] * a;
    }
    __syncthreads();   // only block-wide barrier

    // ---- per-lane W_hh rows (u, 23+u, 46+u) as f16 pairs -> 36 VGPRs ----
    unsigned wrp[3][12];
    float bh[3];
    #pragma unroll
    for (int r = 0; r < 3; ++r) {
        int row = r * 23 + u;   // <= 77 < 80
        #pragma unroll
        for (int k = 0; k < 12; ++k)
            wrp[r][k] = *(const unsigned*)&whh_h[row * 24 + 2 * k];
        bh[r] = bhh_s[row];
    }
    // b_ih folded into D tile: per-lane bias for D col n = t*16+m
    float bi5[5];
    #pragma unroll
    for (int t = 0; t < 5; ++t) bi5[t] = bih_s[t * 16 + m];

    float an8[L0 ? 8 : 1], cn8[L0 ? 8 : 1];
    if constexpr (L0) {
        #pragma unroll
        for (int j = 0; j < 8; ++j) {
            an8[j] = an_s[kg * 8 + j];
            cn8[j] = cn_s[kg * 8 + j];
        }
    }

    float* xw = &xg_s[wv][0];
    _Float16* hw = &hist_h[wv * 9 * 2 * 24];
    const int ngroups = (lastOnly && dir == 1) ? 1 : 64;
    float hold = 0.f;

    // A-row coords: m = bl_a*8 + tl
    const int bl_a = m >> 3, tl = m & 7;
    const int b_a  = blockIdx.x * 8 + wv * 2 + bl_a;

    for (int g = 0; g < ngroups; ++g) {
        const int tg_a = dir ? (511 - (g * 8 + tl)) : (g * 8 + tl);

        // ---- input-side gates via MFMA (B-frags re-read from LDS) ----
        f32x4 acc[5];
        #pragma unroll
        for (int t = 0; t < 5; ++t) acc[t] = (f32x4){0.f, 0.f, 0.f, 0.f};

        if constexpr (L0) {
            const float* xr = (const float*)in_ + ((size_t)b_a * TT + tg_a) * 32 + kg * 8;
            float4 x0 = *(const float4*)xr;
            float4 x1 = *(const float4*)(xr + 4);
            float xv[8] = {x0.x, x0.y, x0.z, x0.w, x1.x, x1.y, x1.z, x1.w};
            bf16x8 afr;
            #pragma unroll
            for (int j = 0; j < 8; ++j)
                afr[j] = (short)f2bf(xv[j] * an8[j] + cn8[j]);
            #pragma unroll
            for (int t = 0; t < 5; ++t) {
                bf16x8 b0 = *(const bf16x8*)&wih_lds[(t * 16 + m) * 72 + kg * 8];
                acc[t] = __builtin_amdgcn_mfma_f32_16x16x32_bf16(afr, b0,
                                                                 acc[t], 0, 0, 0);
            }
        } else {
            const unsigned short* r0 = (const unsigned short*)in_;
            const unsigned short* r1 = r0 + DSTRIDE;
            size_t rowoff = ((size_t)b_a * TT + tg_a) * 24;
            // frag0: k 0..31 -> kg<3: fwd[8kg..]; kg==3: bwd[0..7]
            const unsigned short* p0 =
                (kg < 3) ? (r0 + rowoff + 8 * kg) : (r1 + rowoff);
            bf16x8 a0 = *(const bf16x8*)p0;
            // frag1: k 32..63 -> kg==0: bwd[8..15]; kg==1: bwd[16..23]; else 0
            const unsigned short* p1 =
                (kg == 0) ? (r1 + rowoff + 8) : (r1 + rowoff + 16);
            bf16x8 a1 = *(const bf16x8*)p1;
            if (kg >= 2) a1 = (bf16x8){0, 0, 0, 0, 0, 0, 0, 0};
            #pragma unroll
            for (int t = 0; t < 5; ++t) {
                bf16x8 b0 = *(const bf16x8*)&wih_lds[(t * 16 + m) * 72 + kg * 8];
                bf16x8 b1 = *(const bf16x8*)&wih_lds[(t * 16 + m) * 72 + 32 + kg * 8];
                acc[t] = __builtin_amdgcn_mfma_f32_16x16x32_bf16(a0, b0,
                                                                 acc[t], 0, 0, 0);
                acc[t] = __builtin_amdgcn_mfma_f32_16x16x32_bf16(a1, b1,
                                                                 acc[t], 0, 0, 0);
            }
        }

        // ---- D (+b_ih) -> per-wave LDS tile [m2][84] ----
        lgkm0(); wbar();                 // prev group's xg reads retired
        #pragma unroll
        for (int t = 0; t < 5; ++t) {
            #pragma unroll
            for (int reg = 0; reg < 4; ++reg) {
                int m2 = kg * 4 + reg;   // D row = (lane>>4)*4+reg
                int n  = t * 16 + m;     // D col = lane&15
                xw[m2 * 84 + n] = acc[t][reg] + bi5[t];
            }
        }
        lgkm0(); wbar();

        // ---- 8 scan steps, within-wave fences only ----
        #pragma unroll
        for (int s8 = 0; s8 < 8; ++s8) {
            const _Float16* hr = &hw[(s8 * 2 + bl) * 24];   // prev h (f16)
            uint4 hq0 = *(const uint4*)hr;          // f16 0..7
            uint4 hq1 = *(const uint4*)(hr + 8);    // f16 8..15
            uint4 hq2 = *(const uint4*)(hr + 16);   // f16 16..23
            unsigned hword[12] = {hq0.x, hq0.y, hq0.z, hq0.w,
                                  hq1.x, hq1.y, hq1.z, hq1.w,
                                  hq2.x, hq2.y, hq2.z, hq2.w};
            float a0 = bh[0], a1 = bh[1], a2 = bh[2];
            #pragma unroll
            for (int k = 0; k < 12; ++k) {
                f16x2 hv = asf16x2(hword[k]);
                a0 = __builtin_amdgcn_fdot2(asf16x2(wrp[0][k]), hv, a0, false);
                a1 = __builtin_amdgcn_fdot2(asf16x2(wrp[1][k]), hv, a1, false);
                a2 = __builtin_amdgcn_fdot2(asf16x2(wrp[2][k]), hv, a2, false);
            }
            const float* xr2 = &xw[(bl * 8 + s8) * 84];
            float xg0 = xr2[u], xg1 = xr2[23 + u], xg2 = xr2[46 + u];
            float r_ = sigm(xg0 + a0);
            float z_ = sigm(xg1 + a1);
            float n_ = tanh_(__builtin_fmaf(r_, a2, xg2));
            float hnew = n_ + z_ * (hold - n_);
            hold = hnew;
            if (lastOnly && u < 23) {
                int tg = dir ? (511 - (g * 8 + s8)) : (g * 8 + s8);
                if (tg == TT - 1) lastbuf[bg * 48 + dir * 23 + u] = hnew;
            }
            wbar();
            if (u < 24) hw[((s8 + 1) * 2 + bl) * 24 + u] = (_Float16)hnew;
            lgkm0(); wbar();
        }

        // ---- cooperative coalesced store of the 8-step block ----
        if (!lastOnly) {
            int b2 = lane >> 5, idx = lane & 31;
            int bb2 = blockIdx.x * 8 + wv * 2 + b2;
            unsigned short* dst =
                (unsigned short*)outbuf + dir * DSTRIDE + (size_t)bb2 * TT * 24;
            #pragma unroll
            for (int c = 0; c < 3; ++c) {
                int p = idx + 32 * c;             // 0..95
                int s = p / 12, cp = p - 12 * s;  // step, col-pair
                f16x2 pf = asf16x2(
                    *(const unsigned*)&hw[((s + 1) * 2 + b2) * 24 + 2 * cp]);
                float lo = (float)pf[0];
                float hi = (cp == 11) ? 0.f : (float)pf[1];   // col 23 := 0
                unsigned pack = (unsigned)f2bf(lo) | ((unsigned)f2bf(hi) << 16);
                int tg = dir ? (511 - (g * 8 + s)) : (g * 8 + s);
                *(unsigned*)(dst + (size_t)tg * 24 + 2 * cp) = pack;
            }
        }
        // carry h into row 0 for next group
        if (u < 24) hw[bl * 24 + u] = (_Float16)hold;
    }
}

__global__ __launch_bounds__(256) void fc_kernel(
    const float* __restrict__ last, const float* __restrict__ fcw,
    const float* __restrict__ fcb, const float* __restrict__ ostd,
    const float* __restrict__ omean, float* __restrict__ out)
{
    int idx = blockIdx.x * 256 + threadIdx.x;
    if (idx >= BB * NOUT) return;
    int b = idx >> 3, o = idx & 7;
    float acc = fcb[o];
    const float* lr = last + b * 48;
    const float* wr = fcw + o * 46;
    #pragma unroll
    for (int i = 0; i < 46; i++) acc += lr[i] * wr[i];
    out[idx] = acc * ostd[o] + omean[o];
}

extern "C" void kernel_launch(void* const* d_in, const int* in_sizes, int n_in,
                              void* d_out, int out_size, void* d_ws,
                              size_t ws_size, hipStream_t stream)
{
    const float* x     = (const float*)d_in[0];
    const float* fmean = (const float*)d_in[1];
    const float* fstd  = (const float*)d_in[2];
    const float* omean = (const float*)d_in[3];
    const float* ostd  = (const float*)d_in[4];
    const float* wih0  = (const float*)d_in[5];
    const float* whh0  = (const float*)d_in[6];
    const float* bih0  = (const float*)d_in[7];
    const float* bhh0  = (const float*)d_in[8];
    const float* wihr  = (const float*)d_in[9];
    const float* whhr  = (const float*)d_in[10];
    const float* bihr  = (const float*)d_in[11];
    const float* bhhr  = (const float*)d_in[12];
    const float* fcw   = (const float*)d_in[13];
    const float* fcb   = (const float*)d_in[14];

    char* ws = (char*)d_ws;
    const size_t bufBytes = 2 * DSTRIDE * sizeof(__hip_bfloat16);  // 96 MiB
    __hip_bfloat16* buf0 = (__hip_bfloat16*)ws;
    __hip_bfloat16* buf1 = (__hip_bfloat16*)(ws + bufBytes);
    float* lastb         = (float*)(ws + 2 * bufBytes);

    dim3 grid(BB / 8, 2);

    gru_mfma<true><<<grid, 256, 0, stream>>>(x, fmean, fstd, wih0, whh0, bih0,
                                             bhh0, buf0, nullptr, 0);
    gru_mfma<false><<<grid, 256, 0, stream>>>(
        buf0, nullptr, nullptr, wihr + 0 * 2 * 69 * 46, whhr + 0 * 2 * 69 * 23,
        bihr + 0 * 2 * 69, bhhr + 0 * 2 * 69, buf1, nullptr, 0);
    gru_mfma<false><<<grid, 256, 0, stream>>>(
        buf1, nullptr, nullptr, wihr + 1 * 2 * 69 * 46, whhr + 1 * 2 * 69 * 23,
        bihr + 1 * 2 * 69, bhhr + 1 * 2 * 69, nullptr, lastb, 1);
    fc_kernel<<<(BB * NOUT + 255) / 256, 256, 0, stream>>>(lastb, fcw, fcb, ostd,
                                                           omean, (float*)d_out);
}

// Round 7
// 885.463 us; speedup vs baseline: 2.9573x; 1.0732x over previous
//
#include <hip/hip_runtime.h>
#include <hip/hip_bf16.h>

constexpr int TT = 512, BB = 2048, NOUT = 8;
constexpr size_t DSTRIDE = (size_t)BB * TT * 24;   // bf16 elems per dir region

typedef __attribute__((ext_vector_type(8))) short bf16x8;
typedef __attribute__((ext_vector_type(4))) float f32x4;
typedef __attribute__((ext_vector_type(2))) _Float16 f16x2;

__device__ __forceinline__ float sigm(float x) {
    return 1.f / (1.f + exp2f(x * -1.4426950408889634f));
}
__device__ __forceinline__ float tanh_(float x) {
    return 1.f - 2.f / (exp2f(x * 2.8853900817779268f) + 1.f);
}
__device__ __forceinline__ unsigned short f2bf(float x) {
    __hip_bfloat16 h = __float2bfloat16(x);
    unsigned short s;
    __builtin_memcpy(&s, &h, 2);
    return s;
}
__device__ __forceinline__ f16x2 asf16x2(unsigned v) {
    f16x2 r; __builtin_memcpy(&r, &v, 4); return r;
}
__device__ __forceinline__ void wbar() { __builtin_amdgcn_wave_barrier(); }

// Wave-autonomous BiGRU layer; input gates via MFMA, hidden matvec via
// v_dot2_f32_f16. Steady state relies on the LDS pipe's in-order execution of
// one wave's DS ops (write->read needs no lgkmcnt fence; only data waits,
// which the compiler inserts). A-fragments software-pipelined one group ahead.
// block = 256 = 4 waves; wave owns 2 batch elems. grid = (BB/8, 2).
template <bool L0>
__global__ __launch_bounds__(256) void gru_mfma(
    const void* __restrict__ in_,        // L0: x [B][T][32] f32; else region0 (region1 at +DSTRIDE)
    const float* __restrict__ fmean, const float* __restrict__ fstd,
    const float* __restrict__ wih_g, const float* __restrict__ whh_g,
    const float* __restrict__ bih_g, const float* __restrict__ bhh_g,
    __hip_bfloat16* __restrict__ outbuf, float* __restrict__ lastbuf,
    int lastOnly)
{
    constexpr int KIN = L0 ? 32 : 46;

    __shared__ __align__(16) short     wih_lds[80 * 72];   // B^T bf16, stride 72
    __shared__ __align__(16) _Float16  whh_h[80 * 24];     // W_hh f16
    __shared__ __align__(16) float     xg_s[4][16 * 84];   // per-wave D tile
    __shared__ __align__(16) _Float16  hist_h[4 * 9 * 2 * 24];  // h history f16
    __shared__ float bih_s[80], bhh_s[80];
    __shared__ __align__(16) float an_s[32], cn_s[32];

    const int tid = threadIdx.x, wv = tid >> 6, lane = tid & 63;
    const int bl = lane >> 5, u = lane & 31;
    const int m  = lane & 15, kg = lane >> 4;             // MFMA lane coords
    const int dir = blockIdx.y;
    const int bg  = blockIdx.x * 8 + wv * 2 + bl;

    const float* wih_d = wih_g + dir * 69 * KIN;
    const float* whh_d = whh_g + dir * 69 * 23;

    // ---- stage W_ih as bf16 B^T [80][72], col-remapped ----
    for (int idx = tid; idx < 80 * 72; idx += 256) {
        int n = idx / 72, k = idx - n * 72;
        float v = 0.f;
        if (n < 69 && k < 64) {
            if constexpr (L0) {
                if (k < 32) v = wih_d[n * 32 + k];
            } else {
                if (k < 23) v = wih_d[n * 46 + k];                      // fwd
                else if (k >= 24 && k < 47) v = wih_d[n * 46 + k - 1];  // bwd
            }
        }
        wih_lds[idx] = (short)f2bf(v);
    }
    for (int idx = tid; idx < 80 * 24; idx += 256) {
        int j = idx / 24, k = idx - j * 24;
        whh_h[idx] = (j < 69 && k < 23) ? (_Float16)whh_d[j * 23 + k]
                                        : (_Float16)0.f;
    }
    for (int idx = tid; idx < 80; idx += 256) {
        bih_s[idx] = (idx < 69) ? bih_g[dir * 69 + idx] : 0.f;
        bhh_s[idx] = (idx < 69) ? bhh_g[dir * 69 + idx] : 0.f;
    }
    for (int idx = tid; idx < 4 * 9 * 2 * 24; idx += 256)
        hist_h[idx] = (_Float16)0.f;
    if (L0 && tid < 32) {
        float sd = fstd[tid];
        float sa = (sd == 0.f) ? 1.f : sd;        // std==0 -> 1
        float a  = (sa == 1.f) ? 0.f : 1.f / sa;  // adjusted std==1 -> zero
        an_s[tid] = a;
        cn_s[tid] = -fmean[tid] * a;
    }
    __syncthreads();   // only block-wide barrier

    // ---- per-lane W_hh rows (u, 23+u, 46+u) as f16 pairs -> 36 VGPRs ----
    unsigned wrp[3][12];
    float bh[3];
    #pragma unroll
    for (int r = 0; r < 3; ++r) {
        int row = r * 23 + u;   // <= 77 < 80
        #pragma unroll
        for (int k = 0; k < 12; ++k)
            wrp[r][k] = *(const unsigned*)&whh_h[row * 24 + 2 * k];
        bh[r] = bhh_s[row];
    }
    // b_ih folded into D tile: per-lane bias for D col n = t*16+m
    float bi5[5];
    #pragma unroll
    for (int t = 0; t < 5; ++t) bi5[t] = bih_s[t * 16 + m];

    float an8[L0 ? 8 : 1], cn8[L0 ? 8 : 1];
    if constexpr (L0) {
        #pragma unroll
        for (int j = 0; j < 8; ++j) {
            an8[j] = an_s[kg * 8 + j];
            cn8[j] = cn_s[kg * 8 + j];
        }
    }

    float* xw = &xg_s[wv][0];
    _Float16* hw = &hist_h[wv * 9 * 2 * 24];
    const int ngroups = (lastOnly && dir == 1) ? 1 : 64;
    float hold = 0.f;

    // A-row coords: m = bl_a*8 + tl
    const int bl_a = m >> 3, tl = m & 7;
    const int b_a  = blockIdx.x * 8 + wv * 2 + bl_a;

    const unsigned short* r0 = (const unsigned short*)in_;
    const unsigned short* r1 = r0 + DSTRIDE;

    // ---- prefetch A-fragment raw data for group 0 ----
    float4 xraw0, xraw1;                 // L0 raw x
    bf16x8 a0r, a1r;                     // !L0 bf16 frags
    {
        const int tg_a = dir ? (511 - tl) : tl;
        if constexpr (L0) {
            const float* xr = (const float*)in_ +
                              ((size_t)b_a * TT + tg_a) * 32 + kg * 8;
            xraw0 = *(const float4*)xr;
            xraw1 = *(const float4*)(xr + 4);
        } else {
            size_t rowoff = ((size_t)b_a * TT + tg_a) * 24;
            const unsigned short* p0 =
                (kg < 3) ? (r0 + rowoff + 8 * kg) : (r1 + rowoff);
            const unsigned short* p1 =
                (kg == 0) ? (r1 + rowoff + 8) : (r1 + rowoff + 16);
            a0r = *(const bf16x8*)p0;
            a1r = *(const bf16x8*)p1;
        }
    }

    for (int g = 0; g < ngroups; ++g) {
        // ---- build A-frags from prefetched raw ----
        f32x4 acc[5];
        #pragma unroll
        for (int t = 0; t < 5; ++t) acc[t] = (f32x4){0.f, 0.f, 0.f, 0.f};

        bf16x8 afr, a0u, a1u;
        if constexpr (L0) {
            float xv[8] = {xraw0.x, xraw0.y, xraw0.z, xraw0.w,
                           xraw1.x, xraw1.y, xraw1.z, xraw1.w};
            #pragma unroll
            for (int j = 0; j < 8; ++j)
                afr[j] = (short)f2bf(xv[j] * an8[j] + cn8[j]);
        } else {
            a0u = a0r;
            a1u = (kg >= 2) ? (bf16x8){0, 0, 0, 0, 0, 0, 0, 0} : a1r;
        }

        // ---- issue next group's A loads (hidden behind MFMA + scan) ----
        if (g + 1 < ngroups) {
            const int tg_n = dir ? (511 - ((g + 1) * 8 + tl)) : ((g + 1) * 8 + tl);
            if constexpr (L0) {
                const float* xr = (const float*)in_ +
                                  ((size_t)b_a * TT + tg_n) * 32 + kg * 8;
                xraw0 = *(const float4*)xr;
                xraw1 = *(const float4*)(xr + 4);
            } else {
                size_t rowoff = ((size_t)b_a * TT + tg_n) * 24;
                const unsigned short* p0 =
                    (kg < 3) ? (r0 + rowoff + 8 * kg) : (r1 + rowoff);
                const unsigned short* p1 =
                    (kg == 0) ? (r1 + rowoff + 8) : (r1 + rowoff + 16);
                a0r = *(const bf16x8*)p0;
                a1r = *(const bf16x8*)p1;
            }
        }

        // ---- MFMA (B-frags re-read from LDS each group) ----
        #pragma unroll
        for (int t = 0; t < 5; ++t) {
            bf16x8 b0 = *(const bf16x8*)&wih_lds[(t * 16 + m) * 72 + kg * 8];
            if constexpr (L0) {
                acc[t] = __builtin_amdgcn_mfma_f32_16x16x32_bf16(afr, b0,
                                                                 acc[t], 0, 0, 0);
            } else {
                bf16x8 b1 = *(const bf16x8*)&wih_lds[(t * 16 + m) * 72 + 32 + kg * 8];
                acc[t] = __builtin_amdgcn_mfma_f32_16x16x32_bf16(a0u, b0,
                                                                 acc[t], 0, 0, 0);
                acc[t] = __builtin_amdgcn_mfma_f32_16x16x32_bf16(a1u, b1,
                                                                 acc[t], 0, 0, 0);
            }
        }

        // ---- D (+b_ih) -> per-wave LDS tile [m2][84] ----
        // In-order DS pipe: prev group's xg reads (issued earlier) complete
        // before these writes; wbar stops compiler reordering.
        wbar();
        #pragma unroll
        for (int t = 0; t < 5; ++t) {
            #pragma unroll
            for (int reg = 0; reg < 4; ++reg) {
                int m2 = kg * 4 + reg;   // D row = (lane>>4)*4+reg
                int n  = t * 16 + m;     // D col = lane&15
                xw[m2 * 84 + n] = acc[t][reg] + bi5[t];
            }
        }
        wbar();

        // ---- prefetch this group's xg (3 rows x 8 steps) into registers ----
        float xgr[8][3];
        #pragma unroll
        for (int s = 0; s < 8; ++s) {
            const float* xr2 = &xw[(bl * 8 + s) * 84];
            xgr[s][0] = xr2[u];
            xgr[s][1] = xr2[23 + u];
            xgr[s][2] = xr2[46 + u];
        }

        // ---- 8 scan steps; only h write+read in LDS, no explicit waits ----
        #pragma unroll
        for (int s8 = 0; s8 < 8; ++s8) {
            const _Float16* hr = &hw[(s8 * 2 + bl) * 24];   // prev h (f16)
            uint4 hq0 = *(const uint4*)hr;          // f16 0..7
            uint4 hq1 = *(const uint4*)(hr + 8);    // f16 8..15
            uint4 hq2 = *(const uint4*)(hr + 16);   // f16 16..23
            // dual accumulators per gate: 6-deep chains
            float a0a = bh[0], a1a = bh[1], a2a = bh[2];
            float a0b = 0.f, a1b = 0.f, a2b = 0.f;
            unsigned hwd[12] = {hq0.x, hq0.y, hq0.z, hq0.w,
                                hq1.x, hq1.y, hq1.z, hq1.w,
                                hq2.x, hq2.y, hq2.z, hq2.w};
            #pragma unroll
            for (int k = 0; k < 6; ++k) {
                f16x2 hv = asf16x2(hwd[k]);
                a0a = __builtin_amdgcn_fdot2(asf16x2(wrp[0][k]), hv, a0a, false);
                a1a = __builtin_amdgcn_fdot2(asf16x2(wrp[1][k]), hv, a1a, false);
                a2a = __builtin_amdgcn_fdot2(asf16x2(wrp[2][k]), hv, a2a, false);
            }
            #pragma unroll
            for (int k = 6; k < 12; ++k) {
                f16x2 hv = asf16x2(hwd[k]);
                a0b = __builtin_amdgcn_fdot2(asf16x2(wrp[0][k]), hv, a0b, false);
                a1b = __builtin_amdgcn_fdot2(asf16x2(wrp[1][k]), hv, a1b, false);
                a2b = __builtin_amdgcn_fdot2(asf16x2(wrp[2][k]), hv, a2b, false);
            }
            float a0 = a0a + a0b, a1 = a1a + a1b, a2 = a2a + a2b;
            float r_ = sigm(xgr[s8][0] + a0);
            float z_ = sigm(xgr[s8][1] + a1);
            float n_ = tanh_(__builtin_fmaf(r_, a2, xgr[s8][2]));
            float hnew = n_ + z_ * (hold - n_);
            hold = hnew;
            if (lastOnly && u < 23) {
                int tg = dir ? (511 - (g * 8 + s8)) : (g * 8 + s8);
                if (tg == TT - 1) lastbuf[bg * 48 + dir * 23 + u] = hnew;
            }
            wbar();
            if (u < 24) hw[((s8 + 1) * 2 + bl) * 24 + u] = (_Float16)hnew;
            wbar();   // next step's reads stay after this write (in-order DS)
        }

        // ---- cooperative coalesced store of the 8-step block ----
        if (!lastOnly) {
            int b2 = lane >> 5, idx = lane & 31;
            int bb2 = blockIdx.x * 8 + wv * 2 + b2;
            unsigned short* dst =
                (unsigned short*)outbuf + dir * DSTRIDE + (size_t)bb2 * TT * 24;
            #pragma unroll
            for (int c = 0; c < 3; ++c) {
                int p = idx + 32 * c;             // 0..95
                int s = p / 12, cp = p - 12 * s;  // step, col-pair
                f16x2 pf = asf16x2(
                    *(const unsigned*)&hw[((s + 1) * 2 + b2) * 24 + 2 * cp]);
                float lo = (float)pf[0];
                float hi = (cp == 11) ? 0.f : (float)pf[1];   // col 23 := 0
                unsigned pack = (unsigned)f2bf(lo) | ((unsigned)f2bf(hi) << 16);
                int tg = dir ? (511 - (g * 8 + s)) : (g * 8 + s);
                *(unsigned*)(dst + (size_t)tg * 24 + 2 * cp) = pack;
            }
        }
        // carry h into row 0 for next group (disjoint from store-phase rows)
        if (u < 24) hw[bl * 24 + u] = (_Float16)hold;
        wbar();
    }
}

__global__ __launch_bounds__(256) void fc_kernel(
    const float* __restrict__ last, const float* __restrict__ fcw,
    const float* __restrict__ fcb, const float* __restrict__ ostd,
    const float* __restrict__ omean, float* __restrict__ out)
{
    int idx = blockIdx.x * 256 + threadIdx.x;
    if (idx >= BB * NOUT) return;
    int b = idx >> 3, o = idx & 7;
    float acc = fcb[o];
    const float* lr = last + b * 48;
    const float* wr = fcw + o * 46;
    #pragma unroll
    for (int i = 0; i < 46; i++) acc += lr[i] * wr[i];
    out[idx] = acc * ostd[o] + omean[o];
}

extern "C" void kernel_launch(void* const* d_in, const int* in_sizes, int n_in,
                              void* d_out, int out_size, void* d_ws,
                              size_t ws_size, hipStream_t stream)
{
    const float* x     = (const float*)d_in[0];
    const float* fmean = (const float*)d_in[1];
    const float* fstd  = (const float*)d_in[2];
    const float* omean = (const float*)d_in[3];
    const float* ostd  = (const float*)d_in[4];
    const float* wih0  = (const float*)d_in[5];
    const float* whh0  = (const float*)d_in[6];
    const float* bih0  = (const float*)d_in[7];
    const float* bhh0  = (const float*)d_in[8];
    const float* wihr  = (const float*)d_in[9];
    const float* whhr  = (const float*)d_in[10];
    const float* bihr  = (const float*)d_in[11];
    const float* bhhr  = (const float*)d_in[12];
    const float* fcw   = (const float*)d_in[13];
    const float* fcb   = (const float*)d_in[14];

    char* ws = (char*)d_ws;
    const size_t bufBytes = 2 * DSTRIDE * sizeof(__hip_bfloat16);  // 96 MiB
    __hip_bfloat16* buf0 = (__hip_bfloat16*)ws;
    __hip_bfloat16* buf1 = (__hip_bfloat16*)(ws + bufBytes);
    float* lastb         = (float*)(ws + 2 * bufBytes);

    dim3 grid(BB / 8, 2);

    gru_mfma<true><<<grid, 256, 0, stream>>>(x, fmean, fstd, wih0, whh0, bih0,
                                             bhh0, buf0, nullptr, 0);
    gru_mfma<false><<<grid, 256, 0, stream>>>(
        buf0, nullptr, nullptr, wihr + 0 * 2 * 69 * 46, whhr + 0 * 2 * 69 * 23,
        bihr + 0 * 2 * 69, bhhr + 0 * 2 * 69, buf1, nullptr, 0);
    gru_mfma<false><<<grid, 256, 0, stream>>>(
        buf1, nullptr, nullptr, wihr + 1 * 2 * 69 * 46, whhr + 1 * 2 * 69 * 23,
        bihr + 1 * 2 * 69, bhhr + 1 * 2 * 69, nullptr, lastb, 1);
    fc_kernel<<<(BB * NOUT + 255) / 256, 256, 0, stream>>>(lastb, fcw, fcb, ostd,
                                                           omean, (float*)d_out);
}